// Round 1
// baseline (2520.598 us; speedup 1.0000x reference)
//
#include <hip/hip_runtime.h>
#include <hip/hip_bf16.h>
#include <stdint.h>

// Problem constants (from reference)
#define N_TOK 4096
#define DDIM  2048
#define VOCAB 50257
#define IGNORE_INDEX (-100)

// Tiling
#define BM 128
#define BN 128
#define BK 64
#define VCHUNKS ((VOCAB + BN - 1) / BN)   // 393
#define ROW_TILES (N_TOK / BM)            // 32

typedef float f32x4 __attribute__((ext_vector_type(4)));
typedef short bf16x8 __attribute__((ext_vector_type(8)));

__device__ __forceinline__ uint32_t pack2bf(float a, float b) {
  // round-to-nearest-even fp32 -> bf16, packed pair
  uint32_t ua = __float_as_uint(a);
  uint32_t ub = __float_as_uint(b);
  uint32_t ra = (ua + 0x7fffu + ((ua >> 16) & 1u)) >> 16;
  uint32_t rb = (ub + 0x7fffu + ((ub >> 16) & 1u)) & 0xffff0000u;
  return (ra & 0xffffu) | rb;
}

// ---------------------------------------------------------------------------
// Kernel 1: fused GEMM tile + per-(row, V-chunk) online-softmax partials.
// Computes D[n][m] = sum_k w[k][n] * x[m][k] via mfma (A-operand = weight,
// B-operand = x), then per-row max / sum-exp over the 128 vocab columns of
// this chunk, plus captures the target logit.
// ---------------------------------------------------------------------------
__global__ __launch_bounds__(256, 2) void lmhead_partial(
    const float* __restrict__ x, const float* __restrict__ w,
    const int* __restrict__ tgt,
    float2* __restrict__ partial, float* __restrict__ tlogit)
{
  __shared__ uint4 xs[BM * BK * 2 / 16];   // 16 KB: x tile, [m][k] bf16, swizzled
  __shared__ uint4 wt[BN * BK * 2 / 16];   // 16 KB: w tile, [n][k] bf16 (transposed), swizzled
  __shared__ float2 stats[2][BM];

  const int bid = blockIdx.x;
  const int v  = bid >> 5;        // chunk-major: consecutive blocks share weight panel
  const int r  = bid & 31;
  const int v0 = v * BN;
  const int m0 = r * BM;
  const int tid  = threadIdx.x;
  const int lane = tid & 63;
  const int wid  = tid >> 6;
  const int wn = wid >> 1, wm = wid & 1;   // 2x2 waves: wn = vocab half, wm = token half
  const int lr = lane & 15, lk = lane >> 4;

  f32x4 acc[4][4];
  #pragma unroll
  for (int i = 0; i < 4; ++i)
    #pragma unroll
    for (int j = 0; j < 4; ++j) acc[i][j] = (f32x4)0.f;

  char* xsb = (char*)xs;
  char* wtb = (char*)wt;

  for (int kt = 0; kt < DDIM / BK; ++kt) {
    const int k0 = kt * BK;
    __syncthreads();
    // ---- stage x tile: 128 rows x 64 k, fp32->bf16, linear-in-k layout ----
    #pragma unroll
    for (int i = 0; i < 4; ++i) {
      int t = tid + i * 256;              // 0..1023
      int m = t >> 3, kg = t & 7;         // 8 floats per task
      const float* gp = x + (size_t)(m0 + m) * DDIM + k0 + kg * 8;
      float4 f0 = *(const float4*)gp;
      float4 f1 = *(const float4*)(gp + 4);
      uint4 pk;
      pk.x = pack2bf(f0.x, f0.y); pk.y = pack2bf(f0.z, f0.w);
      pk.z = pack2bf(f1.x, f1.y); pk.w = pack2bf(f1.z, f1.w);
      int byte = (m * 128 + kg * 16) ^ ((m & 7) << 4);
      *(uint4*)(xsb + byte) = pk;
    }
    // ---- stage w tile transposed: [n][k] bf16; 8 k-strided coalesced loads ----
    #pragma unroll
    for (int i = 0; i < 4; ++i) {
      int t = tid + i * 256;
      int n = t & 127, kg = t >> 7;
      int col = v0 + n;
      float f[8];
      if (col < VOCAB) {
        const float* gp = w + (size_t)(k0 + kg * 8) * VOCAB + col;
        #pragma unroll
        for (int kk = 0; kk < 8; ++kk) f[kk] = gp[(size_t)kk * VOCAB];
      } else {
        #pragma unroll
        for (int kk = 0; kk < 8; ++kk) f[kk] = 0.f;
      }
      uint4 pk;
      pk.x = pack2bf(f[0], f[1]); pk.y = pack2bf(f[2], f[3]);
      pk.z = pack2bf(f[4], f[5]); pk.w = pack2bf(f[6], f[7]);
      int byte = (n * 128 + kg * 16) ^ ((n & 7) << 4);
      *(uint4*)(wtb + byte) = pk;
    }
    __syncthreads();
    // ---- compute: 2 k-steps of 16x16x32, 16 mfma each ----
    #pragma unroll
    for (int ks = 0; ks < 2; ++ks) {
      bf16x8 af[4], bfr[4];
      #pragma unroll
      for (int bi = 0; bi < 4; ++bi) {
        int row = wn * 64 + bi * 16 + lr;
        int byte = (row * 128 + ks * 64 + lk * 16) ^ ((row & 7) << 4);
        af[bi] = *(const bf16x8*)(wtb + byte);
      }
      #pragma unroll
      for (int bj = 0; bj < 4; ++bj) {
        int row = wm * 64 + bj * 16 + lr;
        int byte = (row * 128 + ks * 64 + lk * 16) ^ ((row & 7) << 4);
        bfr[bj] = *(const bf16x8*)(xsb + byte);
      }
      #pragma unroll
      for (int bi = 0; bi < 4; ++bi)
        #pragma unroll
        for (int bj = 0; bj < 4; ++bj)
          acc[bi][bj] = __builtin_amdgcn_mfma_f32_16x16x32_bf16(
              af[bi], bfr[bj], acc[bi][bj], 0, 0, 0);
    }
  }

  // ---- epilogue: per-row (m) max & sum-exp over this wave's 64 n's ----
  // C/D layout: row(M=n) = lk*4 + reg, col(N=m) = lr   [m89-verified]
  #pragma unroll
  for (int bj = 0; bj < 4; ++bj) {
    const int m_g = m0 + wm * 64 + bj * 16 + lr;
    float vmax = -INFINITY;
    #pragma unroll
    for (int bi = 0; bi < 4; ++bi) {
      #pragma unroll
      for (int rg = 0; rg < 4; ++rg) {
        int n_g = v0 + wn * 64 + bi * 16 + lk * 4 + rg;
        if (n_g < VOCAB) vmax = fmaxf(vmax, acc[bi][bj][rg]);
      }
    }
    vmax = fmaxf(vmax, __shfl_xor(vmax, 16, 64));
    vmax = fmaxf(vmax, __shfl_xor(vmax, 32, 64));
    float ssum = 0.f;
    const int t = tgt[m_g];
    #pragma unroll
    for (int bi = 0; bi < 4; ++bi) {
      #pragma unroll
      for (int rg = 0; rg < 4; ++rg) {
        int n_g = v0 + wn * 64 + bi * 16 + lk * 4 + rg;
        float val = acc[bi][bj][rg];
        if (n_g < VOCAB) ssum += __expf(val - vmax);
        if (n_g == t) tlogit[m_g] = val;   // exactly one lane/reg grid-wide
      }
    }
    ssum += __shfl_xor(ssum, 16, 64);
    ssum += __shfl_xor(ssum, 32, 64);
    if (lk == 0) stats[wn][wm * 64 + bj * 16 + lr] = make_float2(vmax, ssum);
  }
  __syncthreads();
  // merge the two vocab-half waves, write partial
  if (tid < BM) {
    float2 a = stats[0][tid], b = stats[1][tid];
    float M = fmaxf(a.x, b.x);
    float S = a.y * __expf(a.x - M) + b.y * __expf(b.x - M);
    partial[(size_t)(m0 + tid) * VCHUNKS + v] = make_float2(M, S);
  }
}

// ---------------------------------------------------------------------------
// Kernel 2: per-row merge of 393 chunk partials -> lse; loss = lse - tgt_logit;
// masked sum into d_out[0].
// ---------------------------------------------------------------------------
__device__ __forceinline__ void lse_merge(float& m, float& s, float M, float S) {
  if (S > 0.f) {
    if (M > m) { s = s * __expf(m - M) + S; m = M; }
    else       { s += S * __expf(M - m); }
  }
}

__global__ void lmhead_reduce(const float2* __restrict__ partial,
                              const float* __restrict__ tlogit,
                              const int* __restrict__ tgt,
                              float* __restrict__ out)
{
  const int wid  = threadIdx.x >> 6;
  const int lane = threadIdx.x & 63;
  const int row  = blockIdx.x * 4 + wid;
  float m = -INFINITY, s = 0.f;
  for (int c = lane; c < VCHUNKS; c += 64) {
    float2 p = partial[(size_t)row * VCHUNKS + c];
    lse_merge(m, s, p.x, p.y);
  }
  #pragma unroll
  for (int off = 1; off < 64; off <<= 1) {
    float M = __shfl_xor(m, off, 64);
    float S = __shfl_xor(s, off, 64);
    lse_merge(m, s, M, S);
  }
  if (lane == 0) {
    int t = tgt[row];
    if (t != IGNORE_INDEX) {
      float loss = m + __logf(s) - tlogit[row];
      atomicAdd(out, loss);
    }
  }
}

extern "C" void kernel_launch(void* const* d_in, const int* in_sizes, int n_in,
                              void* d_out, int out_size, void* d_ws, size_t ws_size,
                              hipStream_t stream) {
  const float* x = (const float*)d_in[0];
  const float* w = (const float*)d_in[1];
  const int* tgt = (const int*)d_in[2];
  float* out = (float*)d_out;

  // ws layout: [N*VCHUNKS float2 partials | N float target-logits] ~= 12.9 MB
  float2* partial = (float2*)d_ws;
  float* tlogit = (float*)((char*)d_ws + (size_t)N_TOK * VCHUNKS * sizeof(float2));

  hipMemsetAsync(d_out, 0, sizeof(float), stream);
  lmhead_partial<<<dim3(VCHUNKS * ROW_TILES), 256, 0, stream>>>(x, w, tgt, partial, tlogit);
  lmhead_reduce<<<dim3(N_TOK / 4), 256, 0, stream>>>(partial, tlogit, tgt, out);
}

// Round 2
// 959.173 us; speedup vs baseline: 2.6279x; 2.6279x over previous
//
#include <hip/hip_runtime.h>
#include <hip/hip_bf16.h>
#include <stdint.h>

// Problem constants (from reference)
#define N_TOK 4096
#define DDIM  2048
#define VOCAB 50257
#define IGNORE_INDEX (-100)

// Tiling
#define BM 128
#define BN 128
#define BK 64
#define VCHUNKS ((VOCAB + BN - 1) / BN)   // 393
#define VP (VCHUNKS * BN)                 // 50304 padded vocab
#define ROW_TILES (N_TOK / BM)            // 32

typedef float f32x4 __attribute__((ext_vector_type(4)));
typedef short bf16x8 __attribute__((ext_vector_type(8)));

__device__ __forceinline__ uint32_t pack2bf(float a, float b) {
  // round-to-nearest-even fp32 -> bf16, packed pair
  uint32_t ua = __float_as_uint(a);
  uint32_t ub = __float_as_uint(b);
  uint32_t ra = (ua + 0x7fffu + ((ua >> 16) & 1u)) >> 16;
  uint32_t rb = (ub + 0x7fffu + ((ub >> 16) & 1u)) & 0xffff0000u;
  return (ra & 0xffffu) | rb;
}

__device__ __forceinline__ void gload_lds16(const void* g, void* l) {
  __builtin_amdgcn_global_load_lds(
      (const __attribute__((address_space(1))) uint32_t*)g,
      (__attribute__((address_space(3))) uint32_t*)l, 16, 0, 0);
}

// ---------------------------------------------------------------------------
// Prep 1: x fp32[N][D] -> bf16[N][D]
// ---------------------------------------------------------------------------
__global__ __launch_bounds__(256) void convert_x(const float* __restrict__ x,
                                                 ushort* __restrict__ xb) {
  int t = blockIdx.x * 256 + threadIdx.x;   // N*D/8 threads
  float4 f0 = ((const float4*)x)[(size_t)t * 2];
  float4 f1 = ((const float4*)x)[(size_t)t * 2 + 1];
  uint4 pk;
  pk.x = pack2bf(f0.x, f0.y); pk.y = pack2bf(f0.z, f0.w);
  pk.z = pack2bf(f1.x, f1.y); pk.w = pack2bf(f1.z, f1.w);
  ((uint4*)xb)[t] = pk;
}

// ---------------------------------------------------------------------------
// Prep 2: w fp32[D][V] -> wt bf16[VP][D] (transpose, zero-pad v >= VOCAB)
// ---------------------------------------------------------------------------
__global__ __launch_bounds__(256) void transpose_w(const float* __restrict__ w,
                                                   ushort* __restrict__ wt) {
  __shared__ float t[64][65];
  const int vb = blockIdx.x * 64;   // VP/64 = 786 blocks
  const int kb = blockIdx.y * 64;   // D/64  = 32 blocks
  const int tid = threadIdx.x;
  const int tv = tid & 63, tk4 = tid >> 6;
  #pragma unroll
  for (int i = 0; i < 16; ++i) {
    int kl = tk4 + i * 4;
    int v = vb + tv;
    float val = (v < VOCAB) ? w[(size_t)(kb + kl) * VOCAB + v] : 0.f;
    t[kl][tv] = val;
  }
  __syncthreads();
  const int k2 = tid & 31, v8 = tid >> 5;
  #pragma unroll
  for (int i = 0; i < 8; ++i) {
    int vl = v8 + i * 8;
    uint32_t pk = pack2bf(t[k2 * 2][vl], t[k2 * 2 + 1][vl]);
    *(uint32_t*)(wt + (size_t)(vb + vl) * DDIM + kb + k2 * 2) = pk;
  }
}

// ---------------------------------------------------------------------------
// Main: bf16 GEMM (m97 structure: global_load_lds w16, swizzled LDS) fused
// with per-(row, V-chunk) online-softmax partials.
// A-operand = wt[VP][D], B-operand = xb[N][D]. D[n][m] layout per round-1.
// ---------------------------------------------------------------------------
__global__ __launch_bounds__(256, 2) void lmhead_main(
    const ushort* __restrict__ wt, const ushort* __restrict__ xb,
    const int* __restrict__ tgt,
    float2* __restrict__ partial, float* __restrict__ tlogit)
{
  __shared__ char lds[32768];          // A tile [0,16K), B tile [16K,32K)
  __shared__ float2 stats[2][BM];

  const int bid = blockIdx.x;
  const int v = bid >> 5;              // chunk-major: 32 row-tiles share a panel
  const int r = bid & 31;
  const int v0 = v * BN;
  const int m0 = r * BM;
  const int tid = threadIdx.x;
  const int lane = tid & 63;
  const int wid = tid >> 6;
  const int wn = wid >> 1, wm = wid & 1;
  const int lr = lane & 15, lk = lane >> 4;

  f32x4 acc[4][4];
  #pragma unroll
  for (int i = 0; i < 4; ++i)
    #pragma unroll
    for (int j = 0; j < 4; ++j) acc[i][j] = (f32x4)0.f;

  char* Al = lds;
  char* Bl = lds + 16384;

  // Staging source: 1KB chunk = 8 rows x 128B. lane -> row lane>>3, column
  // (16B units) inverse-swizzled so that swizzled ds_read sees linear data.
  const int srow = lane >> 3;
  const int scol = (lane & 7) ^ srow;           // involution of the read XOR
  const ushort* wsrc = wt + (size_t)(v0 + srow) * DDIM + scol * 8;
  const ushort* xsrc = xb + (size_t)(m0 + srow) * DDIM + scol * 8;

  for (int kt = 0; kt < DDIM / BK; ++kt) {
    const int k0 = kt * BK;
    #pragma unroll
    for (int i = 0; i < 4; ++i) {
      int c = wid * 4 + i;                       // chunk 0..15 (8 rows each)
      gload_lds16(wsrc + (size_t)c * 8 * DDIM + k0, Al + c * 1024);
    }
    #pragma unroll
    for (int i = 0; i < 4; ++i) {
      int c = wid * 4 + i;
      gload_lds16(xsrc + (size_t)c * 8 * DDIM + k0, Bl + c * 1024);
    }
    __syncthreads();                             // drains vmcnt -> LDS ready
    #pragma unroll
    for (int ks = 0; ks < 2; ++ks) {
      bf16x8 af[4], bfr[4];
      #pragma unroll
      for (int bi = 0; bi < 4; ++bi) {
        int row = wn * 64 + bi * 16 + lr;
        int byte = (row * 128 + ks * 64 + lk * 16) ^ ((row & 7) << 4);
        af[bi] = *(const bf16x8*)(Al + byte);
      }
      #pragma unroll
      for (int bj = 0; bj < 4; ++bj) {
        int row = wm * 64 + bj * 16 + lr;
        int byte = (row * 128 + ks * 64 + lk * 16) ^ ((row & 7) << 4);
        bfr[bj] = *(const bf16x8*)(Bl + byte);
      }
      #pragma unroll
      for (int bi = 0; bi < 4; ++bi)
        #pragma unroll
        for (int bj = 0; bj < 4; ++bj)
          acc[bi][bj] = __builtin_amdgcn_mfma_f32_16x16x32_bf16(
              af[bi], bfr[bj], acc[bi][bj], 0, 0, 0);
    }
    __syncthreads();                             // before overwriting LDS
  }

  // Epilogue: per-row max & sum-exp over this wave's 64 vocab cols.
  // C/D layout: row(M=n) = lk*4 + reg, col(N=m) = lr  [round-1 verified]
  #pragma unroll
  for (int bj = 0; bj < 4; ++bj) {
    const int m_g = m0 + wm * 64 + bj * 16 + lr;
    float vmax = -INFINITY;
    #pragma unroll
    for (int bi = 0; bi < 4; ++bi) {
      #pragma unroll
      for (int rg = 0; rg < 4; ++rg) {
        int n_g = v0 + wn * 64 + bi * 16 + lk * 4 + rg;
        if (n_g < VOCAB) vmax = fmaxf(vmax, acc[bi][bj][rg]);
      }
    }
    vmax = fmaxf(vmax, __shfl_xor(vmax, 16, 64));
    vmax = fmaxf(vmax, __shfl_xor(vmax, 32, 64));
    float ssum = 0.f;
    const int t = tgt[m_g];
    #pragma unroll
    for (int bi = 0; bi < 4; ++bi) {
      #pragma unroll
      for (int rg = 0; rg < 4; ++rg) {
        int n_g = v0 + wn * 64 + bi * 16 + lk * 4 + rg;
        float val = acc[bi][bj][rg];
        if (n_g < VOCAB) ssum += __expf(val - vmax);
        if (n_g == t) tlogit[m_g] = val;
      }
    }
    ssum += __shfl_xor(ssum, 16, 64);
    ssum += __shfl_xor(ssum, 32, 64);
    if (lk == 0) stats[wn][wm * 64 + bj * 16 + lr] = make_float2(vmax, ssum);
  }
  __syncthreads();
  if (tid < BM) {
    float2 a = stats[0][tid], b = stats[1][tid];
    float M = fmaxf(a.x, b.x);
    float S = a.y * __expf(a.x - M) + b.y * __expf(b.x - M);
    partial[(size_t)(m0 + tid) * VCHUNKS + v] = make_float2(M, S);
  }
}

// ---------------------------------------------------------------------------
// Fallback (round-1 kernel): used only if ws_size can't hold bf16 copies.
// ---------------------------------------------------------------------------
__global__ __launch_bounds__(256, 2) void lmhead_partial_fb(
    const float* __restrict__ x, const float* __restrict__ w,
    const int* __restrict__ tgt,
    float2* __restrict__ partial, float* __restrict__ tlogit)
{
  __shared__ uint4 xs[BM * BK * 2 / 16];
  __shared__ uint4 wtl[BN * BK * 2 / 16];
  __shared__ float2 stats[2][BM];

  const int bid = blockIdx.x;
  const int v = bid >> 5;
  const int r = bid & 31;
  const int v0 = v * BN;
  const int m0 = r * BM;
  const int tid = threadIdx.x;
  const int lane = tid & 63;
  const int wid = tid >> 6;
  const int wn = wid >> 1, wm = wid & 1;
  const int lr = lane & 15, lk = lane >> 4;

  f32x4 acc[4][4];
  #pragma unroll
  for (int i = 0; i < 4; ++i)
    #pragma unroll
    for (int j = 0; j < 4; ++j) acc[i][j] = (f32x4)0.f;

  char* xsb = (char*)xs;
  char* wtb = (char*)wtl;

  for (int kt = 0; kt < DDIM / BK; ++kt) {
    const int k0 = kt * BK;
    __syncthreads();
    #pragma unroll
    for (int i = 0; i < 4; ++i) {
      int t = tid + i * 256;
      int m = t >> 3, kg = t & 7;
      const float* gp = x + (size_t)(m0 + m) * DDIM + k0 + kg * 8;
      float4 f0 = *(const float4*)gp;
      float4 f1 = *(const float4*)(gp + 4);
      uint4 pk;
      pk.x = pack2bf(f0.x, f0.y); pk.y = pack2bf(f0.z, f0.w);
      pk.z = pack2bf(f1.x, f1.y); pk.w = pack2bf(f1.z, f1.w);
      int byte = (m * 128 + kg * 16) ^ ((m & 7) << 4);
      *(uint4*)(xsb + byte) = pk;
    }
    #pragma unroll
    for (int i = 0; i < 4; ++i) {
      int t = tid + i * 256;
      int n = t & 127, kg = t >> 7;
      int col = v0 + n;
      float f[8];
      if (col < VOCAB) {
        const float* gp = w + (size_t)(k0 + kg * 8) * VOCAB + col;
        #pragma unroll
        for (int kk = 0; kk < 8; ++kk) f[kk] = gp[(size_t)kk * VOCAB];
      } else {
        #pragma unroll
        for (int kk = 0; kk < 8; ++kk) f[kk] = 0.f;
      }
      uint4 pk;
      pk.x = pack2bf(f[0], f[1]); pk.y = pack2bf(f[2], f[3]);
      pk.z = pack2bf(f[4], f[5]); pk.w = pack2bf(f[6], f[7]);
      int byte = (n * 128 + kg * 16) ^ ((n & 7) << 4);
      *(uint4*)(wtb + byte) = pk;
    }
    __syncthreads();
    #pragma unroll
    for (int ks = 0; ks < 2; ++ks) {
      bf16x8 af[4], bfr[4];
      #pragma unroll
      for (int bi = 0; bi < 4; ++bi) {
        int row = wn * 64 + bi * 16 + lr;
        int byte = (row * 128 + ks * 64 + lk * 16) ^ ((row & 7) << 4);
        af[bi] = *(const bf16x8*)(wtb + byte);
      }
      #pragma unroll
      for (int bj = 0; bj < 4; ++bj) {
        int row = wm * 64 + bj * 16 + lr;
        int byte = (row * 128 + ks * 64 + lk * 16) ^ ((row & 7) << 4);
        bfr[bj] = *(const bf16x8*)(xsb + byte);
      }
      #pragma unroll
      for (int bi = 0; bi < 4; ++bi)
        #pragma unroll
        for (int bj = 0; bj < 4; ++bj)
          acc[bi][bj] = __builtin_amdgcn_mfma_f32_16x16x32_bf16(
              af[bi], bfr[bj], acc[bi][bj], 0, 0, 0);
    }
  }

  #pragma unroll
  for (int bj = 0; bj < 4; ++bj) {
    const int m_g = m0 + wm * 64 + bj * 16 + lr;
    float vmax = -INFINITY;
    #pragma unroll
    for (int bi = 0; bi < 4; ++bi) {
      #pragma unroll
      for (int rg = 0; rg < 4; ++rg) {
        int n_g = v0 + wn * 64 + bi * 16 + lk * 4 + rg;
        if (n_g < VOCAB) vmax = fmaxf(vmax, acc[bi][bj][rg]);
      }
    }
    vmax = fmaxf(vmax, __shfl_xor(vmax, 16, 64));
    vmax = fmaxf(vmax, __shfl_xor(vmax, 32, 64));
    float ssum = 0.f;
    const int t = tgt[m_g];
    #pragma unroll
    for (int bi = 0; bi < 4; ++bi) {
      #pragma unroll
      for (int rg = 0; rg < 4; ++rg) {
        int n_g = v0 + wn * 64 + bi * 16 + lk * 4 + rg;
        float val = acc[bi][bj][rg];
        if (n_g < VOCAB) ssum += __expf(val - vmax);
        if (n_g == t) tlogit[m_g] = val;
      }
    }
    ssum += __shfl_xor(ssum, 16, 64);
    ssum += __shfl_xor(ssum, 32, 64);
    if (lk == 0) stats[wn][wm * 64 + bj * 16 + lr] = make_float2(vmax, ssum);
  }
  __syncthreads();
  if (tid < BM) {
    float2 a = stats[0][tid], b = stats[1][tid];
    float M = fmaxf(a.x, b.x);
    float S = a.y * __expf(a.x - M) + b.y * __expf(b.x - M);
    partial[(size_t)(m0 + tid) * VCHUNKS + v] = make_float2(M, S);
  }
}

// ---------------------------------------------------------------------------
// Reduce: per-row merge of chunk partials -> lse; loss sum into d_out[0].
// ---------------------------------------------------------------------------
__device__ __forceinline__ void lse_merge(float& m, float& s, float M, float S) {
  if (S > 0.f) {
    if (M > m) { s = s * __expf(m - M) + S; m = M; }
    else       { s += S * __expf(M - m); }
  }
}

__global__ void lmhead_reduce(const float2* __restrict__ partial,
                              const float* __restrict__ tlogit,
                              const int* __restrict__ tgt,
                              float* __restrict__ out)
{
  const int wid = threadIdx.x >> 6;
  const int lane = threadIdx.x & 63;
  const int row = blockIdx.x * 4 + wid;
  float m = -INFINITY, s = 0.f;
  for (int c = lane; c < VCHUNKS; c += 64) {
    float2 p = partial[(size_t)row * VCHUNKS + c];
    lse_merge(m, s, p.x, p.y);
  }
  #pragma unroll
  for (int off = 1; off < 64; off <<= 1) {
    float M = __shfl_xor(m, off, 64);
    float S = __shfl_xor(s, off, 64);
    lse_merge(m, s, M, S);
  }
  if (lane == 0) {
    int t = tgt[row];
    if (t != IGNORE_INDEX) {
      float loss = m + __logf(s) - tlogit[row];
      atomicAdd(out, loss);
    }
  }
}

extern "C" void kernel_launch(void* const* d_in, const int* in_sizes, int n_in,
                              void* d_out, int out_size, void* d_ws, size_t ws_size,
                              hipStream_t stream) {
  const float* x = (const float*)d_in[0];
  const float* w = (const float*)d_in[1];
  const int* tgt = (const int*)d_in[2];
  float* out = (float*)d_out;

  const size_t wt_bytes = (size_t)VP * DDIM * 2;         // ~196.5 MB
  const size_t xb_bytes = (size_t)N_TOK * DDIM * 2;      // 16 MB
  const size_t part_bytes = (size_t)N_TOK * VCHUNKS * 8; // ~12.3 MB
  const size_t tl_bytes = (size_t)N_TOK * 4;
  const size_t need = wt_bytes + xb_bytes + part_bytes + tl_bytes;

  hipMemsetAsync(d_out, 0, sizeof(float), stream);

  if (ws_size >= need) {
    ushort* wt = (ushort*)d_ws;
    ushort* xb = (ushort*)((char*)d_ws + wt_bytes);
    float2* partial = (float2*)((char*)d_ws + wt_bytes + xb_bytes);
    float* tlogit = (float*)((char*)d_ws + wt_bytes + xb_bytes + part_bytes);

    convert_x<<<dim3(N_TOK * DDIM / 8 / 256), 256, 0, stream>>>(x, xb);
    transpose_w<<<dim3(VP / 64, DDIM / 64), 256, 0, stream>>>(w, wt);
    lmhead_main<<<dim3(VCHUNKS * ROW_TILES), 256, 0, stream>>>(wt, xb, tgt, partial, tlogit);
    lmhead_reduce<<<dim3(N_TOK / 4), 256, 0, stream>>>(partial, tlogit, tgt, out);
  } else {
    float2* partial = (float2*)d_ws;
    float* tlogit = (float*)((char*)d_ws + part_bytes);
    lmhead_partial_fb<<<dim3(VCHUNKS * ROW_TILES), 256, 0, stream>>>(x, w, tgt, partial, tlogit);
    lmhead_reduce<<<dim3(N_TOK / 4), 256, 0, stream>>>(partial, tlogit, tgt, out);
  }
}